// Round 1
// baseline (1040.215 us; speedup 1.0000x reference)
//
#include <hip/hip_runtime.h>
#include <float.h>
#include <math.h>

#define BATCH 8
#define NPTS 4096
#define KNN 10
#define BN (BATCH * NPTS)

// Eigenvector of the smallest eigenvalue of symmetric 3x3 [[a00,a01,a02],[a01,a11,a12],[a02,a12,a22]]
__device__ inline void smallest_eigvec(float a00, float a01, float a02,
                                       float a11, float a12, float a22,
                                       float& vx, float& vy, float& vz) {
    float p1 = a01 * a01 + a02 * a02 + a12 * a12;
    float q = (a00 + a11 + a22) * (1.0f / 3.0f);
    float b00 = a00 - q, b11 = a11 - q, b22 = a22 - q;
    float p2 = b00 * b00 + b11 * b11 + b22 * b22 + 2.0f * p1;
    float p = sqrtf(p2 * (1.0f / 6.0f));
    if (p < 1e-20f) {  // (near-)scalar matrix: any unit vector is an eigenvector
        vx = 1.0f; vy = 0.0f; vz = 0.0f;
        return;
    }
    float ip = 1.0f / p;
    float c00 = b00 * ip, c01 = a01 * ip, c02 = a02 * ip;
    float c11 = b11 * ip, c12 = a12 * ip, c22 = b22 * ip;
    float detB = c00 * (c11 * c22 - c12 * c12)
               - c01 * (c01 * c22 - c12 * c02)
               + c02 * (c01 * c12 - c11 * c02);
    float r = 0.5f * detB;
    r = fminf(1.0f, fmaxf(-1.0f, r));
    float phi = acosf(r) * (1.0f / 3.0f);
    float lmin = q + 2.0f * p * cosf(phi + 2.0943951023931953f);  // phi + 2*pi/3

    float m00 = a00 - lmin, m11 = a11 - lmin, m22 = a22 - lmin;
    // rows of (A - lmin*I)
    float r0x = m00, r0y = a01, r0z = a02;
    float r1x = a01, r1y = m11, r1z = a12;
    float r2x = a02, r2y = a12, r2z = m22;
    // cross products of row pairs -> null-space candidates
    float c0x = r0y * r1z - r0z * r1y, c0y = r0z * r1x - r0x * r1z, c0z = r0x * r1y - r0y * r1x;
    float c1x = r0y * r2z - r0z * r2y, c1y = r0z * r2x - r0x * r2z, c1z = r0x * r2y - r0y * r2x;
    float c2x = r1y * r2z - r1z * r2y, c2y = r1z * r2x - r1x * r2z, c2z = r1x * r2y - r1y * r2x;
    float n0 = c0x * c0x + c0y * c0y + c0z * c0z;
    float n1 = c1x * c1x + c1y * c1y + c1z * c1z;
    float n2 = c2x * c2x + c2y * c2y + c2z * c2z;
    float bx = c0x, by = c0y, bz = c0z, bn = n0;
    if (n1 > bn) { bx = c1x; by = c1y; bz = c1z; bn = n1; }
    if (n2 > bn) { bx = c2x; by = c2y; bz = c2z; bn = n2; }
    if (bn < 1e-30f) { vx = 1.0f; vy = 0.0f; vz = 0.0f; return; }
    float inv = rsqrtf(bn);
    vx = bx * inv; vy = by * inv; vz = bz * inv;
}

// One block of 256 threads handles 256 points of one (cloud, batch).
// Full cloud staged in LDS as float4(x,y,z,|x|^2) = 64 KiB.
__global__ __launch_bounds__(256) void knn_normals_kernel(
    const float* __restrict__ pred, const float* __restrict__ gt,
    float* __restrict__ normals /* [2][3][BN] SoA */) {
    __shared__ float4 pts[NPTS];

    const int b = blockIdx.y;
    const int cloud = blockIdx.z;
    const float* base = (cloud == 0 ? pred : gt) + b * 3 * NPTS;
    const int tid = threadIdx.x;

    for (int i = tid; i < NPTS; i += 256) {
        float x = base[i];
        float y = base[NPTS + i];
        float z = base[2 * NPTS + i];
        pts[i] = make_float4(x, y, z, x * x + y * y + z * z);
    }
    __syncthreads();

    const int n = blockIdx.x * 256 + tid;
    const float4 me = pts[n];

    // register-resident top-K (ascending distance), stable on ties (strict <)
    float bd[KNN];
    int bi[KNN];
#pragma unroll
    for (int j = 0; j < KNN; ++j) { bd[j] = FLT_MAX; bi[j] = 0; }

#pragma unroll 4
    for (int m = 0; m < NPTS; ++m) {
        float4 p = pts[m];
        float dot = me.x * p.x + me.y * p.y + me.z * p.z;
        float d = me.w + p.w - 2.0f * dot;  // matches reference d2 formula
        if (d < bd[KNN - 1]) {
            float cd = d;
            int ci = m;
#pragma unroll
            for (int j = 0; j < KNN; ++j) {
                if (cd < bd[j]) {
                    float td = bd[j]; int ti = bi[j];
                    bd[j] = cd; bi[j] = ci;
                    cd = td; ci = ti;
                }
            }
        }
    }

    // gather neighborhood, mean-center, 3x3 covariance / K
    float nx[KNN], ny[KNN], nz[KNN];
    float mx = 0.f, my = 0.f, mz = 0.f;
#pragma unroll
    for (int j = 0; j < KNN; ++j) {
        float4 p = pts[bi[j]];
        nx[j] = p.x; ny[j] = p.y; nz[j] = p.z;
        mx += p.x; my += p.y; mz += p.z;
    }
    mx *= (1.0f / KNN); my *= (1.0f / KNN); mz *= (1.0f / KNN);

    float cxx = 0.f, cxy = 0.f, cxz = 0.f, cyy = 0.f, cyz = 0.f, czz = 0.f;
#pragma unroll
    for (int j = 0; j < KNN; ++j) {
        float dx = nx[j] - mx, dy = ny[j] - my, dz = nz[j] - mz;
        cxx += dx * dx; cxy += dx * dy; cxz += dx * dz;
        cyy += dy * dy; cyz += dy * dz; czz += dz * dz;
    }
    cxx *= (1.0f / KNN); cxy *= (1.0f / KNN); cxz *= (1.0f / KNN);
    cyy *= (1.0f / KNN); cyz *= (1.0f / KNN); czz *= (1.0f / KNN);

    float vx, vy, vz;
    smallest_eigvec(cxx, cxy, cxz, cyy, cyz, czz, vx, vy, vz);

    float* outp = normals + cloud * 3 * BN;
    const int idx = b * NPTS + n;
    outp[idx] = vx;
    outp[BN + idx] = vy;
    outp[2 * BN + idx] = vz;
}

// Single-block deterministic reduction: mean(1 - |cos(pn, gn)|)
__global__ __launch_bounds__(256) void loss_kernel(const float* __restrict__ normals,
                                                   float* __restrict__ out) {
    __shared__ float red[256];
    const float* pn = normals;
    const float* gn = normals + 3 * BN;
    float acc = 0.f;
    for (int i = threadIdx.x; i < BN; i += 256) {
        float px = pn[i], py = pn[BN + i], pz = pn[2 * BN + i];
        float gx = gn[i], gy = gn[BN + i], gz = gn[2 * BN + i];
        float dot = px * gx + py * gy + pz * gz;
        float npn = sqrtf(px * px + py * py + pz * pz);
        float ngn = sqrtf(gx * gx + gy * gy + gz * gz);
        float denom = fmaxf(npn * ngn, 1e-8f);
        float cosv = dot / denom;
        acc += 1.0f - fabsf(cosv);
    }
    red[threadIdx.x] = acc;
    __syncthreads();
    for (int s = 128; s > 0; s >>= 1) {
        if (threadIdx.x < s) red[threadIdx.x] += red[threadIdx.x + s];
        __syncthreads();
    }
    if (threadIdx.x == 0) out[0] = red[0] * (1.0f / BN);
}

extern "C" void kernel_launch(void* const* d_in, const int* in_sizes, int n_in,
                              void* d_out, int out_size, void* d_ws, size_t ws_size,
                              hipStream_t stream) {
    const float* pred = (const float*)d_in[0];
    const float* gt = (const float*)d_in[1];
    float* out = (float*)d_out;
    float* normals = (float*)d_ws;  // 6*BN floats = 786 KiB scratch

    dim3 grid(NPTS / 256, BATCH, 2);
    knn_normals_kernel<<<grid, 256, 0, stream>>>(pred, gt, normals);
    loss_kernel<<<1, 256, 0, stream>>>(normals, out);
}

// Round 2
// 203.559 us; speedup vs baseline: 5.1101x; 5.1101x over previous
//
#include <hip/hip_runtime.h>
#include <float.h>
#include <math.h>

#define BATCH 8
#define NPTS 4096
#define KNN 10
#define BN (BATCH * NPTS)

__device__ inline float med3f(float x, float a, float b) {
    return __builtin_amdgcn_fmed3f(x, a, b);
}

// Eigenvector of the smallest eigenvalue of symmetric 3x3 [[a00,a01,a02],[a01,a11,a12],[a02,a12,a22]]
__device__ inline void smallest_eigvec(float a00, float a01, float a02,
                                       float a11, float a12, float a22,
                                       float& vx, float& vy, float& vz) {
    float p1 = a01 * a01 + a02 * a02 + a12 * a12;
    float q = (a00 + a11 + a22) * (1.0f / 3.0f);
    float b00 = a00 - q, b11 = a11 - q, b22 = a22 - q;
    float p2 = b00 * b00 + b11 * b11 + b22 * b22 + 2.0f * p1;
    float p = sqrtf(p2 * (1.0f / 6.0f));
    if (p < 1e-20f) { vx = 1.0f; vy = 0.0f; vz = 0.0f; return; }
    float ip = 1.0f / p;
    float c00 = b00 * ip, c01 = a01 * ip, c02 = a02 * ip;
    float c11 = b11 * ip, c12 = a12 * ip, c22 = b22 * ip;
    float detB = c00 * (c11 * c22 - c12 * c12)
               - c01 * (c01 * c22 - c12 * c02)
               + c02 * (c01 * c12 - c11 * c02);
    float r = 0.5f * detB;
    r = fminf(1.0f, fmaxf(-1.0f, r));
    float phi = acosf(r) * (1.0f / 3.0f);
    float lmin = q + 2.0f * p * cosf(phi + 2.0943951023931953f);  // + 2*pi/3

    float m00 = a00 - lmin, m11 = a11 - lmin, m22 = a22 - lmin;
    float r0x = m00, r0y = a01, r0z = a02;
    float r1x = a01, r1y = m11, r1z = a12;
    float r2x = a02, r2y = a12, r2z = m22;
    float c0x = r0y * r1z - r0z * r1y, c0y = r0z * r1x - r0x * r1z, c0z = r0x * r1y - r0y * r1x;
    float c1x = r0y * r2z - r0z * r2y, c1y = r0z * r2x - r0x * r2z, c1z = r0x * r2y - r0y * r2x;
    float c2x = r1y * r2z - r1z * r2y, c2y = r1z * r2x - r1x * r2z, c2z = r1x * r2y - r1y * r2x;
    float n0 = c0x * c0x + c0y * c0y + c0z * c0z;
    float n1 = c1x * c1x + c1y * c1y + c1z * c1z;
    float n2 = c2x * c2x + c2y * c2y + c2z * c2z;
    float bx = c0x, by = c0y, bz = c0z, bn = n0;
    if (n1 > bn) { bx = c1x; by = c1y; bz = c1z; bn = n1; }
    if (n2 > bn) { bx = c2x; by = c2y; bz = c2z; bn = n2; }
    if (bn < 1e-30f) { vx = 1.0f; vy = 0.0f; vz = 0.0f; return; }
    float inv = rsqrtf(bn);
    vx = bx * inv; vy = by * inv; vz = bz * inv;
}

// Block: 256 threads = 128 points x 2 scan-segments. Cloud staged SoA in LDS (48 KiB).
// Top-10 kept as packed fp32 keys: high 20 bits = truncated distance, low 12 bits = index.
// Branchless sorted insert via v_med3_f32 chain — no divergence, index rides in the key.
__global__ __launch_bounds__(256, 2) void knn_normals_kernel(
    const float* __restrict__ pred, const float* __restrict__ gt,
    float* __restrict__ normals /* [2][3][BN] SoA */) {
    __shared__ float sx[NPTS], sy[NPTS], sz[NPTS];   // 48 KiB
    __shared__ float keybuf[128 * KNN];              // 5 KiB

    const int b = blockIdx.y;
    const int cloud = blockIdx.z;
    const float* base = (cloud == 0 ? pred : gt) + b * 3 * NPTS;
    const int tid = threadIdx.x;

    for (int i = tid; i < NPTS; i += 256) {
        sx[i] = base[i];
        sy[i] = base[NPTS + i];
        sz[i] = base[2 * NPTS + i];
    }
    __syncthreads();

    const int lp = tid & 127;      // local point id
    const int seg = tid >> 7;      // which half of the cloud this thread scans
    const int pt = blockIdx.x * 128 + lp;
    const float mex = sx[pt], mey = sy[pt], mez = sz[pt];

    float k[KNN];
#pragma unroll
    for (int j = 0; j < KNN; ++j) k[j] = FLT_MAX;

    const int m0 = seg * (NPTS / 2);
#pragma unroll 8
    for (int mm = 0; mm < NPTS / 2; ++mm) {
        const int m = m0 + mm;
        float dx = sx[m] - mex;
        float dy = sy[m] - mey;
        float dz = sz[m] - mez;
        float d = dx * dx + dy * dy + dz * dz;       // >= 0 exactly (sum of squares)
        d = fmaxf(d, 1e-20f);                        // keep key a normal float (self pt)
        float key = __uint_as_float((__float_as_uint(d) & 0xFFFFF000u) | (unsigned)m);
        // branchless insert of key into ascending sorted k[0..9], drop largest
#pragma unroll
        for (int j = KNN - 1; j >= 1; --j) k[j] = med3f(key, k[j - 1], k[j]);
        k[0] = fminf(key, k[0]);
    }

    if (seg == 1) {
#pragma unroll
        for (int j = 0; j < KNN; ++j) keybuf[lp * KNN + j] = k[j];
    }
    __syncthreads();

    if (seg == 0) {
        // merge partner segment's sorted 10 via the same chain
#pragma unroll
        for (int jj = 0; jj < KNN; ++jj) {
            float key = keybuf[lp * KNN + jj];
#pragma unroll
            for (int j = KNN - 1; j >= 1; --j) k[j] = med3f(key, k[j - 1], k[j]);
            k[0] = fminf(key, k[0]);
        }

        // extract indices, gather neighborhood from LDS, covariance
        float nx[KNN], ny[KNN], nz[KNN];
        float mx = 0.f, my = 0.f, mz = 0.f;
#pragma unroll
        for (int j = 0; j < KNN; ++j) {
            int idx = (int)(__float_as_uint(k[j]) & 0xFFFu);
            nx[j] = sx[idx]; ny[j] = sy[idx]; nz[j] = sz[idx];
            mx += nx[j]; my += ny[j]; mz += nz[j];
        }
        mx *= (1.0f / KNN); my *= (1.0f / KNN); mz *= (1.0f / KNN);

        float cxx = 0.f, cxy = 0.f, cxz = 0.f, cyy = 0.f, cyz = 0.f, czz = 0.f;
#pragma unroll
        for (int j = 0; j < KNN; ++j) {
            float dx = nx[j] - mx, dy = ny[j] - my, dz = nz[j] - mz;
            cxx += dx * dx; cxy += dx * dy; cxz += dx * dz;
            cyy += dy * dy; cyz += dy * dz; czz += dz * dz;
        }
        cxx *= (1.0f / KNN); cxy *= (1.0f / KNN); cxz *= (1.0f / KNN);
        cyy *= (1.0f / KNN); cyz *= (1.0f / KNN); czz *= (1.0f / KNN);

        float vx, vy, vz;
        smallest_eigvec(cxx, cxy, cxz, cyy, cyz, czz, vx, vy, vz);

        float* outp = normals + cloud * 3 * BN;
        const int oidx = b * NPTS + pt;
        outp[oidx] = vx;
        outp[BN + oidx] = vy;
        outp[2 * BN + oidx] = vz;
    }
}

__global__ void zero_out_kernel(float* __restrict__ out) {
    if (threadIdx.x == 0) out[0] = 0.0f;
}

// 64 blocks x 256 threads; per-block LDS reduction + one atomicAdd
__global__ __launch_bounds__(256) void loss_kernel(const float* __restrict__ normals,
                                                   float* __restrict__ out) {
    __shared__ float red[256];
    const float* pn = normals;
    const float* gn = normals + 3 * BN;
    float acc = 0.f;
    for (int i = blockIdx.x * 256 + threadIdx.x; i < BN; i += 64 * 256) {
        float px = pn[i], py = pn[BN + i], pz = pn[2 * BN + i];
        float gx = gn[i], gy = gn[BN + i], gz = gn[2 * BN + i];
        float dot = px * gx + py * gy + pz * gz;
        float npn = sqrtf(px * px + py * py + pz * pz);
        float ngn = sqrtf(gx * gx + gy * gy + gz * gz);
        float denom = fmaxf(npn * ngn, 1e-8f);
        acc += 1.0f - fabsf(dot / denom);
    }
    red[threadIdx.x] = acc;
    __syncthreads();
    for (int s = 128; s > 0; s >>= 1) {
        if (threadIdx.x < s) red[threadIdx.x] += red[threadIdx.x + s];
        __syncthreads();
    }
    if (threadIdx.x == 0) atomicAdd(out, red[0] * (1.0f / BN));
}

extern "C" void kernel_launch(void* const* d_in, const int* in_sizes, int n_in,
                              void* d_out, int out_size, void* d_ws, size_t ws_size,
                              hipStream_t stream) {
    const float* pred = (const float*)d_in[0];
    const float* gt = (const float*)d_in[1];
    float* out = (float*)d_out;
    float* normals = (float*)d_ws;  // 6*BN floats = 786 KiB scratch

    dim3 grid(NPTS / 128, BATCH, 2);
    knn_normals_kernel<<<grid, 256, 0, stream>>>(pred, gt, normals);
    zero_out_kernel<<<1, 64, 0, stream>>>(out);
    loss_kernel<<<64, 256, 0, stream>>>(normals, out);
}

// Round 3
// 180.163 us; speedup vs baseline: 5.7737x; 1.1299x over previous
//
#include <hip/hip_runtime.h>
#include <float.h>
#include <math.h>

#define BATCH 8
#define NPTS 4096
#define KNN 10
#define BN (BATCH * NPTS)
#define QPB 64            // queries per block
#define SEGS 4            // scan segments (one wave each)
#define HALF (NPTS / 2)   // points staged per pass (32 KiB as float4)
#define SEGC (HALF / SEGS)

__device__ inline float med3f(float x, float a, float b) {
    return __builtin_amdgcn_fmed3f(x, a, b);
}

// Eigenvector of smallest eigenvalue of symmetric 3x3
__device__ inline void smallest_eigvec(float a00, float a01, float a02,
                                       float a11, float a12, float a22,
                                       float& vx, float& vy, float& vz) {
    float p1 = a01 * a01 + a02 * a02 + a12 * a12;
    float q = (a00 + a11 + a22) * (1.0f / 3.0f);
    float b00 = a00 - q, b11 = a11 - q, b22 = a22 - q;
    float p2 = b00 * b00 + b11 * b11 + b22 * b22 + 2.0f * p1;
    float p = sqrtf(p2 * (1.0f / 6.0f));
    if (p < 1e-20f) { vx = 1.0f; vy = 0.0f; vz = 0.0f; return; }
    float ip = 1.0f / p;
    float c00 = b00 * ip, c01 = a01 * ip, c02 = a02 * ip;
    float c11 = b11 * ip, c12 = a12 * ip, c22 = b22 * ip;
    float detB = c00 * (c11 * c22 - c12 * c12)
               - c01 * (c01 * c22 - c12 * c02)
               + c02 * (c01 * c12 - c11 * c02);
    float r = 0.5f * detB;
    r = fminf(1.0f, fmaxf(-1.0f, r));
    float phi = acosf(r) * (1.0f / 3.0f);
    float lmin = q + 2.0f * p * cosf(phi + 2.0943951023931953f);

    float m00 = a00 - lmin, m11 = a11 - lmin, m22 = a22 - lmin;
    float r0x = m00, r0y = a01, r0z = a02;
    float r1x = a01, r1y = m11, r1z = a12;
    float r2x = a02, r2y = a12, r2z = m22;
    float c0x = r0y * r1z - r0z * r1y, c0y = r0z * r1x - r0x * r1z, c0z = r0x * r1y - r0y * r1x;
    float c1x = r0y * r2z - r0z * r2y, c1y = r0z * r2x - r0x * r2z, c1z = r0x * r2y - r0y * r2x;
    float c2x = r1y * r2z - r1z * r2y, c2y = r1z * r2x - r1x * r2z, c2z = r1x * r2y - r1y * r2x;
    float n0 = c0x * c0x + c0y * c0y + c0z * c0z;
    float n1 = c1x * c1x + c1y * c1y + c1z * c1z;
    float n2 = c2x * c2x + c2y * c2y + c2z * c2z;
    float bx = c0x, by = c0y, bz = c0z, bnm = n0;
    if (n1 > bnm) { bx = c1x; by = c1y; bz = c1z; bnm = n1; }
    if (n2 > bnm) { bx = c2x; by = c2y; bz = c2z; bnm = n2; }
    if (bnm < 1e-30f) { vx = 1.0f; vy = 0.0f; vz = 0.0f; return; }
    float inv = rsqrtf(bnm);
    vx = bx * inv; vy = by * inv; vz = bz * inv;
}

// 256 threads = 64 queries x 4 segments (one wave per segment -> wave-uniform
// LDS broadcast reads). Cloud staged in two half-passes of float4 (32 KiB), so
// 4 blocks/CU co-reside -> 16 waves/CU for latency hiding.
__global__ __launch_bounds__(256, 4) void knn_normals_kernel(
    const float* __restrict__ pred, const float* __restrict__ gt,
    float* __restrict__ normals /* [2][3][BN] SoA */) {
    __shared__ float4 pts[HALF];                 // 32 KiB
    __shared__ float keybuf[3 * QPB * KNN];      // 7.5 KiB (segs 1..3 dump)

    const int b = blockIdx.y;
    const int cloud = blockIdx.z;
    const float* __restrict__ base = (cloud == 0 ? pred : gt) + b * 3 * NPTS;
    const int tid = threadIdx.x;
    const int q = tid & (QPB - 1);
    const int seg = tid >> 6;                    // wave index = segment
    const int pt = blockIdx.x * QPB + q;

    const float mex = base[pt];
    const float mey = base[NPTS + pt];
    const float mez = base[2 * NPTS + pt];
    const float nmx = -2.0f * mex, nmy = -2.0f * mey, nmz = -2.0f * mez;
    const float smw = mex * mex + mey * mey + mez * mez;

    float k[KNN];
#pragma unroll
    for (int j = 0; j < KNN; ++j) k[j] = FLT_MAX;

    for (int pass = 0; pass < 2; ++pass) {
        const int pb = pass * HALF;
        for (int i = tid; i < HALF; i += 256) {
            float x = base[pb + i];
            float y = base[NPTS + pb + i];
            float z = base[2 * NPTS + pb + i];
            pts[i] = make_float4(x, y, z, x * x + y * y + z * z);
        }
        __syncthreads();

        const int s0 = seg * SEGC;
        const unsigned gbase = (unsigned)(pb + s0);
#pragma unroll 8
        for (int c = 0; c < SEGC; ++c) {
            float4 p = pts[s0 + c];
            // d = |p|^2 + |me|^2 - 2 p.me  (== squared distance, fp-reordered)
            float d = fmaf(p.z, nmz, fmaf(p.y, nmy, fmaf(p.x, nmx, p.w + smw)));
            d = fmaxf(d, 1e-30f);                // keep key normal (self point)
            float key = __uint_as_float((__float_as_uint(d) & 0xFFFFF000u) | (gbase + c));
            // branchless sorted insert (9 independent med3 + fmin)
#pragma unroll
            for (int j = KNN - 1; j >= 1; --j) k[j] = med3f(key, k[j - 1], k[j]);
            k[0] = fminf(key, k[0]);
        }
        __syncthreads();   // scan done before restage / keybuf phase
    }

    if (seg != 0) {
#pragma unroll
        for (int j = 0; j < KNN; ++j) keybuf[((seg - 1) * QPB + q) * KNN + j] = k[j];
    }
    __syncthreads();

    if (seg == 0) {
        // merge segments 1..3
        for (int s = 0; s < 3; ++s) {
#pragma unroll
            for (int jj = 0; jj < KNN; ++jj) {
                float key = keybuf[(s * QPB + q) * KNN + jj];
#pragma unroll
                for (int j = KNN - 1; j >= 1; --j) k[j] = med3f(key, k[j - 1], k[j]);
                k[0] = fminf(key, k[0]);
            }
        }

        // gather neighborhood from global (cloud is L2-resident), covariance
        float nx[KNN], ny[KNN], nz[KNN];
        float mx = 0.f, my = 0.f, mz = 0.f;
#pragma unroll
        for (int j = 0; j < KNN; ++j) {
            int idx = (int)(__float_as_uint(k[j]) & 0xFFFu);
            nx[j] = base[idx]; ny[j] = base[NPTS + idx]; nz[j] = base[2 * NPTS + idx];
            mx += nx[j]; my += ny[j]; mz += nz[j];
        }
        mx *= (1.0f / KNN); my *= (1.0f / KNN); mz *= (1.0f / KNN);

        float cxx = 0.f, cxy = 0.f, cxz = 0.f, cyy = 0.f, cyz = 0.f, czz = 0.f;
#pragma unroll
        for (int j = 0; j < KNN; ++j) {
            float dx = nx[j] - mx, dy = ny[j] - my, dz = nz[j] - mz;
            cxx += dx * dx; cxy += dx * dy; cxz += dx * dz;
            cyy += dy * dy; cyz += dy * dz; czz += dz * dz;
        }
        cxx *= (1.0f / KNN); cxy *= (1.0f / KNN); cxz *= (1.0f / KNN);
        cyy *= (1.0f / KNN); cyz *= (1.0f / KNN); czz *= (1.0f / KNN);

        float vx, vy, vz;
        smallest_eigvec(cxx, cxy, cxz, cyy, cyz, czz, vx, vy, vz);

        float* outp = normals + cloud * 3 * BN;
        const int oidx = b * NPTS + pt;
        outp[oidx] = vx;
        outp[BN + oidx] = vy;
        outp[2 * BN + oidx] = vz;
    }
}

__global__ void zero_out_kernel(float* __restrict__ out) {
    if (threadIdx.x == 0) out[0] = 0.0f;
}

__global__ __launch_bounds__(256) void loss_kernel(const float* __restrict__ normals,
                                                   float* __restrict__ out) {
    __shared__ float red[256];
    const float* pn = normals;
    const float* gn = normals + 3 * BN;
    float acc = 0.f;
    for (int i = blockIdx.x * 256 + threadIdx.x; i < BN; i += 64 * 256) {
        float px = pn[i], py = pn[BN + i], pz = pn[2 * BN + i];
        float gx = gn[i], gy = gn[BN + i], gz = gn[2 * BN + i];
        float dot = px * gx + py * gy + pz * gz;
        float npn = sqrtf(px * px + py * py + pz * pz);
        float ngn = sqrtf(gx * gx + gy * gy + gz * gz);
        float denom = fmaxf(npn * ngn, 1e-8f);
        acc += 1.0f - fabsf(dot / denom);
    }
    red[threadIdx.x] = acc;
    __syncthreads();
    for (int s = 128; s > 0; s >>= 1) {
        if (threadIdx.x < s) red[threadIdx.x] += red[threadIdx.x + s];
        __syncthreads();
    }
    if (threadIdx.x == 0) atomicAdd(out, red[0] * (1.0f / BN));
}

extern "C" void kernel_launch(void* const* d_in, const int* in_sizes, int n_in,
                              void* d_out, int out_size, void* d_ws, size_t ws_size,
                              hipStream_t stream) {
    const float* pred = (const float*)d_in[0];
    const float* gt = (const float*)d_in[1];
    float* out = (float*)d_out;
    float* normals = (float*)d_ws;  // 6*BN floats = 786 KiB scratch

    dim3 grid(NPTS / QPB, BATCH, 2);   // 64 x 8 x 2 = 1024 blocks
    knn_normals_kernel<<<grid, 256, 0, stream>>>(pred, gt, normals);
    zero_out_kernel<<<1, 64, 0, stream>>>(out);
    loss_kernel<<<64, 256, 0, stream>>>(normals, out);
}